// Round 1
// baseline (2482.469 us; speedup 1.0000x reference)
//
#include <hip/hip_runtime.h>

// Problem constants (B=4, C=512, G=32, H=W=64)
#define B_   4
#define C_   512
#define G_   32
#define CPG  16          // channels per group
#define N_   4096        // H*W
#define KT   16          // GEMM K-tile

// ---------------------------------------------------------------------------
// GroupNorm statistics: one block per (b, g). Writes per-channel scale/shift:
//   nx[b,c,n] = x[b,c,n] * scale[b,c] + shift[b,c]
// ---------------------------------------------------------------------------
__global__ __launch_bounds__(256)
void gn_stats_kernel(const float* __restrict__ x,
                     const float* __restrict__ gamma,
                     const float* __restrict__ beta,
                     float* __restrict__ scale,   // [B*C]
                     float* __restrict__ shift)   // [B*C]
{
    int bg = blockIdx.x;            // 0..127
    int b = bg >> 5, g = bg & 31;
    const float* base = x + (size_t)(b * C_ + g * CPG) * N_;
    const int nelem = CPG * N_;     // 65536
    int t = threadIdx.x;

    float s = 0.f, ss = 0.f;
    for (int i = t * 4; i < nelem; i += 256 * 4) {
        float4 v = *reinterpret_cast<const float4*>(base + i);
        s  += v.x + v.y + v.z + v.w;
        ss += v.x * v.x + v.y * v.y + v.z * v.z + v.w * v.w;
    }
    __shared__ float rs[256], rss[256];
    rs[t] = s; rss[t] = ss;
    __syncthreads();
    for (int off = 128; off > 0; off >>= 1) {
        if (t < off) { rs[t] += rs[t + off]; rss[t] += rss[t + off]; }
        __syncthreads();
    }
    __shared__ float mean_s, rstd_s;
    if (t == 0) {
        float mean = rs[0] / (float)nelem;
        float var  = rss[0] / (float)nelem - mean * mean;
        mean_s = mean;
        rstd_s = rsqrtf(var + 1e-6f);
    }
    __syncthreads();
    if (t < CPG) {
        int c = g * CPG + t;
        float sc = gamma[c] * rstd_s;
        scale[b * C_ + c] = sc;
        shift[b * C_ + c] = beta[c] - mean_s * sc;
    }
}

// ---------------------------------------------------------------------------
// QKV projection GEMM with fused GroupNorm on the input operand.
//   out[b,co,n] = bias[co] + sum_ci W[co,ci] * (x[b,ci,n]*scale[b,ci]+shift[b,ci])
// grid: (N/64, C/64, 12) with z = proj*4 + b. 64x64 tile, 4x4 per thread.
// ---------------------------------------------------------------------------
__global__ __launch_bounds__(256)
void qkv_kernel(const float* __restrict__ x,
                const float* __restrict__ scale, const float* __restrict__ shift,
                const float* __restrict__ wq, const float* __restrict__ bq,
                const float* __restrict__ wk, const float* __restrict__ bk,
                const float* __restrict__ wv, const float* __restrict__ bv,
                float* __restrict__ qbuf, float* __restrict__ kbuf,
                float* __restrict__ vbuf)
{
    int z = blockIdx.z;
    int proj = z >> 2, b = z & 3;
    const float* W; const float* bias; float* out;
    if      (proj == 0) { W = wq; bias = bq; out = qbuf; }
    else if (proj == 1) { W = wk; bias = bk; out = kbuf; }
    else                { W = wv; bias = bv; out = vbuf; }
    out += (size_t)b * C_ * N_;
    const float* xb  = x + (size_t)b * C_ * N_;
    const float* scb = scale + b * C_;
    const float* shb = shift + b * C_;

    int n0 = blockIdx.x * 64;
    int m0 = blockIdx.y * 64;          // co
    int t = threadIdx.x;
    int tx = t & 15, ty = t >> 4;

    __shared__ float As[KT][64];       // [ci][co]
    __shared__ float Bs[KT][64];       // [ci][n]
    float acc[4][4] = {};

    for (int k0 = 0; k0 < C_; k0 += KT) {
        // W tile 64(co) x 16(ci) -> As[ci][co], float4 global load
        {
            int idx = t * 4;
            int ci = idx & 15, co = idx >> 4;
            float4 w4 = *reinterpret_cast<const float4*>(W + (size_t)(m0 + co) * C_ + k0 + ci);
            As[ci + 0][co] = w4.x;
            As[ci + 1][co] = w4.y;
            As[ci + 2][co] = w4.z;
            As[ci + 3][co] = w4.w;
        }
        // x tile 16(ci) x 64(n) -> Bs[ci][n], fused GN
        {
            int idx = t * 4;
            int nl = idx & 63, ci = idx >> 6;
            float4 v4 = *reinterpret_cast<const float4*>(xb + (size_t)(k0 + ci) * N_ + n0 + nl);
            float sc = scb[k0 + ci], sh = shb[k0 + ci];
            float4 o; o.x = v4.x * sc + sh; o.y = v4.y * sc + sh;
            o.z = v4.z * sc + sh; o.w = v4.w * sc + sh;
            *reinterpret_cast<float4*>(&Bs[ci][nl]) = o;
        }
        __syncthreads();
        #pragma unroll
        for (int k = 0; k < KT; ++k) {
            float4 a4 = *reinterpret_cast<const float4*>(&As[k][ty * 4]);
            float4 b4 = *reinterpret_cast<const float4*>(&Bs[k][tx * 4]);
            float ar[4] = {a4.x, a4.y, a4.z, a4.w};
            float br[4] = {b4.x, b4.y, b4.z, b4.w};
            #pragma unroll
            for (int mi = 0; mi < 4; ++mi)
                #pragma unroll
                for (int ni = 0; ni < 4; ++ni)
                    acc[mi][ni] += ar[mi] * br[ni];
        }
        __syncthreads();
    }
    #pragma unroll
    for (int mi = 0; mi < 4; ++mi) {
        int co = m0 + ty * 4 + mi;
        float bb = bias[co];
        float4 o = {acc[mi][0] + bb, acc[mi][1] + bb, acc[mi][2] + bb, acc[mi][3] + bb};
        *reinterpret_cast<float4*>(out + (size_t)co * N_ + n0 + tx * 4) = o;
    }
}

// ---------------------------------------------------------------------------
// Attention scores: S[i,j] = (1/sqrt(C)) * sum_c q[c,i]*k[c,j]   (one batch)
// grid: (N/64 j, N/64 i). Both operands read coalesced along spatial dim.
// ---------------------------------------------------------------------------
__global__ __launch_bounds__(256)
void scores_kernel(const float* __restrict__ q, const float* __restrict__ k,
                   float* __restrict__ S)
{
    const float inv_sqrt_c = 0.044194173824159216f;   // 1/sqrt(512)
    int j0 = blockIdx.x * 64;
    int i0 = blockIdx.y * 64;
    int t = threadIdx.x;
    int tx = t & 15, ty = t >> 4;

    __shared__ float As[KT][64];   // [c][i]
    __shared__ float Bs[KT][64];   // [c][j]
    float acc[4][4] = {};

    for (int k0 = 0; k0 < C_; k0 += KT) {
        int idx = t * 4;
        int sl = idx & 63, cl = idx >> 6;
        *reinterpret_cast<float4*>(&As[cl][sl]) =
            *reinterpret_cast<const float4*>(q + (size_t)(k0 + cl) * N_ + i0 + sl);
        *reinterpret_cast<float4*>(&Bs[cl][sl]) =
            *reinterpret_cast<const float4*>(k + (size_t)(k0 + cl) * N_ + j0 + sl);
        __syncthreads();
        #pragma unroll
        for (int kk = 0; kk < KT; ++kk) {
            float4 a4 = *reinterpret_cast<const float4*>(&As[kk][ty * 4]);
            float4 b4 = *reinterpret_cast<const float4*>(&Bs[kk][tx * 4]);
            float ar[4] = {a4.x, a4.y, a4.z, a4.w};
            float br[4] = {b4.x, b4.y, b4.z, b4.w};
            #pragma unroll
            for (int mi = 0; mi < 4; ++mi)
                #pragma unroll
                for (int ni = 0; ni < 4; ++ni)
                    acc[mi][ni] += ar[mi] * br[ni];
        }
        __syncthreads();
    }
    #pragma unroll
    for (int mi = 0; mi < 4; ++mi) {
        int i = i0 + ty * 4 + mi;
        float4 o = {acc[mi][0] * inv_sqrt_c, acc[mi][1] * inv_sqrt_c,
                    acc[mi][2] * inv_sqrt_c, acc[mi][3] * inv_sqrt_c};
        *reinterpret_cast<float4*>(S + (size_t)i * N_ + j0 + tx * 4) = o;
    }
}

// ---------------------------------------------------------------------------
// Row softmax over j. One block per row i; row (16 KB) staged in registers.
// ---------------------------------------------------------------------------
__global__ __launch_bounds__(256)
void softmax_kernel(float* __restrict__ S)
{
    int i = blockIdx.x;
    float* row = S + (size_t)i * N_;
    int t = threadIdx.x;
    __shared__ float red[256];

    float4 v[4];
    float mx = -1e30f;
    #pragma unroll
    for (int e = 0; e < 4; ++e) {
        v[e] = *reinterpret_cast<const float4*>(row + e * 1024 + t * 4);
        mx = fmaxf(mx, fmaxf(fmaxf(v[e].x, v[e].y), fmaxf(v[e].z, v[e].w)));
    }
    red[t] = mx; __syncthreads();
    for (int off = 128; off > 0; off >>= 1) {
        if (t < off) red[t] = fmaxf(red[t], red[t + off]);
        __syncthreads();
    }
    mx = red[0];
    __syncthreads();

    float sum = 0.f;
    #pragma unroll
    for (int e = 0; e < 4; ++e) {
        v[e].x = __expf(v[e].x - mx); v[e].y = __expf(v[e].y - mx);
        v[e].z = __expf(v[e].z - mx); v[e].w = __expf(v[e].w - mx);
        sum += v[e].x + v[e].y + v[e].z + v[e].w;
    }
    red[t] = sum; __syncthreads();
    for (int off = 128; off > 0; off >>= 1) {
        if (t < off) red[t] += red[t + off];
        __syncthreads();
    }
    float inv = 1.f / red[0];
    #pragma unroll
    for (int e = 0; e < 4; ++e) {
        float4 o = {v[e].x * inv, v[e].y * inv, v[e].z * inv, v[e].w * inv};
        *reinterpret_cast<float4*>(row + e * 1024 + t * 4) = o;
    }
}

// ---------------------------------------------------------------------------
// PV: out[c,i] = sum_j v[c,j] * P[i,j]   (one batch)
// grid: (N/64 i, C/64 c). K = N = 4096.
// ---------------------------------------------------------------------------
__global__ __launch_bounds__(256)
void pv_kernel(const float* __restrict__ v, const float* __restrict__ P,
               float* __restrict__ out)
{
    int i0 = blockIdx.x * 64;
    int c0 = blockIdx.y * 64;
    int t = threadIdx.x;
    int tx = t & 15, ty = t >> 4;

    __shared__ float As[KT][64];   // [j][c]
    __shared__ float Bs[KT][64];   // [j][i]
    float acc[4][4] = {};

    for (int k0 = 0; k0 < N_; k0 += KT) {
        int idx = t * 4;
        int jl = idx & 15, rl = idx >> 4;    // rl: c-local for A, i-local for B
        {
            float4 v4 = *reinterpret_cast<const float4*>(v + (size_t)(c0 + rl) * N_ + k0 + jl);
            As[jl + 0][rl] = v4.x; As[jl + 1][rl] = v4.y;
            As[jl + 2][rl] = v4.z; As[jl + 3][rl] = v4.w;
        }
        {
            float4 p4 = *reinterpret_cast<const float4*>(P + (size_t)(i0 + rl) * N_ + k0 + jl);
            Bs[jl + 0][rl] = p4.x; Bs[jl + 1][rl] = p4.y;
            Bs[jl + 2][rl] = p4.z; Bs[jl + 3][rl] = p4.w;
        }
        __syncthreads();
        #pragma unroll
        for (int kk = 0; kk < KT; ++kk) {
            float4 a4 = *reinterpret_cast<const float4*>(&As[kk][ty * 4]);
            float4 b4 = *reinterpret_cast<const float4*>(&Bs[kk][tx * 4]);
            float ar[4] = {a4.x, a4.y, a4.z, a4.w};
            float br[4] = {b4.x, b4.y, b4.z, b4.w};
            #pragma unroll
            for (int mi = 0; mi < 4; ++mi)
                #pragma unroll
                for (int ni = 0; ni < 4; ++ni)
                    acc[mi][ni] += ar[mi] * br[ni];
        }
        __syncthreads();
    }
    #pragma unroll
    for (int mi = 0; mi < 4; ++mi) {
        int c = c0 + ty * 4 + mi;
        float4 o = {acc[mi][0], acc[mi][1], acc[mi][2], acc[mi][3]};
        *reinterpret_cast<float4*>(out + (size_t)c * N_ + i0 + tx * 4) = o;
    }
}

// ---------------------------------------------------------------------------
// Output projection + residual:
//   out[b,co,n] = x[b,co,n] + bo[co] + sum_ci wo[co,ci]*attn[b,ci,n]
// grid: (N/64, C/64, B)
// ---------------------------------------------------------------------------
__global__ __launch_bounds__(256)
void final_kernel(const float* __restrict__ attn,
                  const float* __restrict__ wo, const float* __restrict__ bo,
                  const float* __restrict__ x, float* __restrict__ outp)
{
    int b = blockIdx.z;
    const float* ab = attn + (size_t)b * C_ * N_;
    const float* xb = x + (size_t)b * C_ * N_;
    float* ob = outp + (size_t)b * C_ * N_;

    int n0 = blockIdx.x * 64;
    int m0 = blockIdx.y * 64;
    int t = threadIdx.x;
    int tx = t & 15, ty = t >> 4;

    __shared__ float As[KT][64];   // [ci][co]
    __shared__ float Bs[KT][64];   // [ci][n]
    float acc[4][4] = {};

    for (int k0 = 0; k0 < C_; k0 += KT) {
        {
            int idx = t * 4;
            int ci = idx & 15, co = idx >> 4;
            float4 w4 = *reinterpret_cast<const float4*>(wo + (size_t)(m0 + co) * C_ + k0 + ci);
            As[ci + 0][co] = w4.x; As[ci + 1][co] = w4.y;
            As[ci + 2][co] = w4.z; As[ci + 3][co] = w4.w;
        }
        {
            int idx = t * 4;
            int nl = idx & 63, ci = idx >> 6;
            *reinterpret_cast<float4*>(&Bs[ci][nl]) =
                *reinterpret_cast<const float4*>(ab + (size_t)(k0 + ci) * N_ + n0 + nl);
        }
        __syncthreads();
        #pragma unroll
        for (int kk = 0; kk < KT; ++kk) {
            float4 a4 = *reinterpret_cast<const float4*>(&As[kk][ty * 4]);
            float4 b4 = *reinterpret_cast<const float4*>(&Bs[kk][tx * 4]);
            float ar[4] = {a4.x, a4.y, a4.z, a4.w};
            float br[4] = {b4.x, b4.y, b4.z, b4.w};
            #pragma unroll
            for (int mi = 0; mi < 4; ++mi)
                #pragma unroll
                for (int ni = 0; ni < 4; ++ni)
                    acc[mi][ni] += ar[mi] * br[ni];
        }
        __syncthreads();
    }
    #pragma unroll
    for (int mi = 0; mi < 4; ++mi) {
        int co = m0 + ty * 4 + mi;
        float bb = bo[co];
        const float* xr = xb + (size_t)co * N_ + n0 + tx * 4;
        float4 xv = *reinterpret_cast<const float4*>(xr);
        float4 o = {acc[mi][0] + bb + xv.x, acc[mi][1] + bb + xv.y,
                    acc[mi][2] + bb + xv.z, acc[mi][3] + bb + xv.w};
        *reinterpret_cast<float4*>(ob + (size_t)co * N_ + n0 + tx * 4) = o;
    }
}

// ---------------------------------------------------------------------------
extern "C" void kernel_launch(void* const* d_in, const int* in_sizes, int n_in,
                              void* d_out, int out_size, void* d_ws, size_t ws_size,
                              hipStream_t stream)
{
    const float* x     = (const float*)d_in[0];
    const float* gamma = (const float*)d_in[1];
    const float* beta  = (const float*)d_in[2];
    const float* wq    = (const float*)d_in[3];
    const float* bq    = (const float*)d_in[4];
    const float* wk    = (const float*)d_in[5];
    const float* bk    = (const float*)d_in[6];
    const float* wv    = (const float*)d_in[7];
    const float* bv    = (const float*)d_in[8];
    const float* wo    = (const float*)d_in[9];
    const float* bo    = (const float*)d_in[10];
    float* out = (float*)d_out;

    // Workspace layout (floats):
    //   scale[B*C], shift[B*C], q[B*C*N], k[B*C*N], v[B*C*N], S[N*N]
    // total = 4096 + 3*8388608 + 16777216 floats = ~160 MB
    float* wsf   = (float*)d_ws;
    float* scale = wsf;
    float* shift = wsf + B_ * C_;
    float* qbuf  = wsf + 2 * B_ * C_;
    float* kbuf  = qbuf + (size_t)B_ * C_ * N_;
    float* vbuf  = kbuf + (size_t)B_ * C_ * N_;
    float* Sbuf  = vbuf + (size_t)B_ * C_ * N_;

    gn_stats_kernel<<<128, 256, 0, stream>>>(x, gamma, beta, scale, shift);
    qkv_kernel<<<dim3(N_ / 64, C_ / 64, 12), 256, 0, stream>>>(
        x, scale, shift, wq, bq, wk, bk, wv, bv, qbuf, kbuf, vbuf);

    for (int b = 0; b < B_; ++b) {
        const float* qb = qbuf + (size_t)b * C_ * N_;
        const float* kb = kbuf + (size_t)b * C_ * N_;
        const float* vb = vbuf + (size_t)b * C_ * N_;
        scores_kernel<<<dim3(N_ / 64, N_ / 64), 256, 0, stream>>>(qb, kb, Sbuf);
        softmax_kernel<<<N_, 256, 0, stream>>>(Sbuf);
        // PV output overwrites this batch's q region (no longer needed)
        pv_kernel<<<dim3(N_ / 64, C_ / 64), 256, 0, stream>>>(vb, Sbuf, (float*)qb);
    }

    final_kernel<<<dim3(N_ / 64, C_ / 64, B_), 256, 0, stream>>>(qbuf, wo, bo, x, out);
}

// Round 2
// 456.335 us; speedup vs baseline: 5.4400x; 5.4400x over previous
//
#include <hip/hip_runtime.h>

// Problem constants (B=4, C=512, G=32, H=W=64)
#define B_   4
#define C_   512
#define G_   32
#define CPG  16          // channels per group
#define N_   4096        // H*W

typedef unsigned short u16;
typedef __attribute__((ext_vector_type(4))) float f32x4;
typedef __attribute__((ext_vector_type(8))) short s16x8;
typedef __attribute__((ext_vector_type(8))) u16   u16x8;
typedef __attribute__((ext_vector_type(4))) u16   u16x4;

__device__ __forceinline__ u16 f2bf(float f) {
    union { float f; unsigned u; } x; x.f = f;
    unsigned r = x.u + 0x7fffu + ((x.u >> 16) & 1u);   // RNE
    return (u16)(r >> 16);
}

// ---------------------------------------------------------------------------
// GroupNorm statistics: one block per (b, g). Writes per-channel scale/shift.
// ---------------------------------------------------------------------------
__global__ __launch_bounds__(256)
void gn_stats_kernel(const float* __restrict__ x,
                     const float* __restrict__ gamma,
                     const float* __restrict__ beta,
                     float* __restrict__ scale,   // [B*C]
                     float* __restrict__ shift)   // [B*C]
{
    int bg = blockIdx.x;            // 0..127
    int b = bg >> 5, g = bg & 31;
    const float* base = x + (size_t)(b * C_ + g * CPG) * N_;
    const int nelem = CPG * N_;     // 65536
    int t = threadIdx.x;

    float s = 0.f, ss = 0.f;
    for (int i = t * 4; i < nelem; i += 256 * 4) {
        float4 v = *reinterpret_cast<const float4*>(base + i);
        s  += v.x + v.y + v.z + v.w;
        ss += v.x * v.x + v.y * v.y + v.z * v.z + v.w * v.w;
    }
    __shared__ float rs[256], rss[256];
    rs[t] = s; rss[t] = ss;
    __syncthreads();
    for (int off = 128; off > 0; off >>= 1) {
        if (t < off) { rs[t] += rs[t + off]; rss[t] += rss[t + off]; }
        __syncthreads();
    }
    __shared__ float mean_s, rstd_s;
    if (t == 0) {
        float mean = rs[0] / (float)nelem;
        float var  = rss[0] / (float)nelem - mean * mean;
        mean_s = mean;
        rstd_s = rsqrtf(var + 1e-6f);
    }
    __syncthreads();
    if (t < CPG) {
        int c = g * CPG + t;
        float sc = gamma[c] * rstd_s;
        scale[b * C_ + c] = sc;
        shift[b * C_ + c] = beta[c] - mean_s * sc;
    }
}

// ---------------------------------------------------------------------------
// Convert the four 512x512 weight matrices to bf16 (same [co][ci] layout).
// ---------------------------------------------------------------------------
__global__ __launch_bounds__(256)
void wcvt_kernel(const float* __restrict__ wq, const float* __restrict__ wk,
                 const float* __restrict__ wv, const float* __restrict__ wo,
                 u16* __restrict__ wqb, u16* __restrict__ wkb,
                 u16* __restrict__ wvb, u16* __restrict__ wob)
{
    int idx = (blockIdx.x * 256 + threadIdx.x) * 4;   // 65536 threads cover 262144
    {
        float4 a = *reinterpret_cast<const float4*>(wq + idx);
        u16x4 r = { f2bf(a.x), f2bf(a.y), f2bf(a.z), f2bf(a.w) };
        *reinterpret_cast<u16x4*>(wqb + idx) = r;
    }
    {
        float4 a = *reinterpret_cast<const float4*>(wk + idx);
        u16x4 r = { f2bf(a.x), f2bf(a.y), f2bf(a.z), f2bf(a.w) };
        *reinterpret_cast<u16x4*>(wkb + idx) = r;
    }
    {
        float4 a = *reinterpret_cast<const float4*>(wv + idx);
        u16x4 r = { f2bf(a.x), f2bf(a.y), f2bf(a.z), f2bf(a.w) };
        *reinterpret_cast<u16x4*>(wvb + idx) = r;
    }
    {
        float4 a = *reinterpret_cast<const float4*>(wo + idx);
        u16x4 r = { f2bf(a.x), f2bf(a.y), f2bf(a.z), f2bf(a.w) };
        *reinterpret_cast<u16x4*>(wob + idx) = r;
    }
}

// ---------------------------------------------------------------------------
// GN-apply + transpose + bf16 convert: x[b][c][n] f32 -> nx_t[b][n][c] bf16.
// 64(c) x 64(n) tiles. grid (N/64, C/64, B).
// ---------------------------------------------------------------------------
__global__ __launch_bounds__(256)
void nxt_kernel(const float* __restrict__ x, const float* __restrict__ scale,
                const float* __restrict__ shift, u16* __restrict__ nx_t)
{
    int b  = blockIdx.z;
    int n0 = blockIdx.x * 64, c0 = blockIdx.y * 64;
    const float* xb = x + ((size_t)b * C_ + c0) * N_ + n0;
    u16* ob = nx_t + ((size_t)b * N_ + n0) * C_ + c0;
    int t = threadIdx.x;
    int tx = t & 15, ty = t >> 4;

    __shared__ float tile[64][65];
    #pragma unroll
    for (int r = 0; r < 4; ++r) {
        int c = ty * 4 + r;
        float sc = scale[b * C_ + c0 + c];
        float sh = shift[b * C_ + c0 + c];
        float4 v = *reinterpret_cast<const float4*>(xb + (size_t)c * N_ + tx * 4);
        tile[c][tx * 4 + 0] = v.x * sc + sh;
        tile[c][tx * 4 + 1] = v.y * sc + sh;
        tile[c][tx * 4 + 2] = v.z * sc + sh;
        tile[c][tx * 4 + 3] = v.w * sc + sh;
    }
    __syncthreads();
    // write: thread handles row nn = t>>2, 16 contiguous c at (t&3)*16
    int nn = t >> 2, cc0 = (t & 3) * 16;
    u16x8 o0, o1;
    #pragma unroll
    for (int j = 0; j < 8; ++j) o0[j] = f2bf(tile[cc0 + j][nn]);
    #pragma unroll
    for (int j = 0; j < 8; ++j) o1[j] = f2bf(tile[cc0 + 8 + j][nn]);
    *reinterpret_cast<u16x8*>(ob + (size_t)nn * C_ + cc0)     = o0;
    *reinterpret_cast<u16x8*>(ob + (size_t)nn * C_ + cc0 + 8) = o1;
}

// ---------------------------------------------------------------------------
// TN bf16 MFMA GEMM: D[i][j] = sum_k A[i][k] * B[j][k]
// 128x128 tile, BK=32, 4 waves (2x2), 16x16x32 MFMA, global_load_lds staging.
// EPI: 0 = bf16 out + bias[j]; 1 = bf16 out + bias[i]; 2 = f32 out * scale;
//      3 = f32 out + bias[i] + resid[i][j]; 4 = bf16 out plain.
// ---------------------------------------------------------------------------
template<int EPI>
__device__ __forceinline__
void gemm_dev(const u16* __restrict__ A, const u16* __restrict__ B,
              void* __restrict__ Dp, const float* __restrict__ bias,
              const float* __restrict__ resid,
              int M, int Nn, int K, int lda, int ldb, float scl)
{
    __shared__ u16 As[128 * 32];
    __shared__ u16 Bs[128 * 32];

    const int i0 = blockIdx.y * 128;
    const int j0 = blockIdx.x * 128;
    const int t  = threadIdx.x;
    const int l  = t & 63;
    const int w  = t >> 6;          // wave 0..3
    const int wr = w >> 1;          // i-half
    const int wc = w & 1;           // j-half

    const int srow  = l >> 2;       // staging row within 16-row segment
    const int skoff = (l & 3) * 8;  // staging k element offset

    const int fr = l & 15;          // fragment row/col
    const int fk = (l >> 4) * 8;    // fragment k offset

    f32x4 acc[4][4];
    #pragma unroll
    for (int a = 0; a < 4; ++a)
        #pragma unroll
        for (int b2 = 0; b2 < 4; ++b2) acc[a][b2] = 0.f;

    for (int k0 = 0; k0 < K; k0 += 32) {
        #pragma unroll
        for (int r = 0; r < 2; ++r) {
            int s = r * 4 + w;      // segment 0..7 (16 rows each)
            const u16* ga = A + (size_t)(i0 + s * 16 + srow) * lda + (k0 + skoff);
            __builtin_amdgcn_global_load_lds(
                (const __attribute__((address_space(1))) void*)ga,
                (__attribute__((address_space(3))) void*)&As[s * 512], 16, 0, 0);
            const u16* gb = B + (size_t)(j0 + s * 16 + srow) * ldb + (k0 + skoff);
            __builtin_amdgcn_global_load_lds(
                (const __attribute__((address_space(1))) void*)gb,
                (__attribute__((address_space(3))) void*)&Bs[s * 512], 16, 0, 0);
        }
        __syncthreads();

        s16x8 af[4], bfr[4];
        #pragma unroll
        for (int mi = 0; mi < 4; ++mi)
            af[mi] = *reinterpret_cast<const s16x8*>(&As[(wr * 64 + mi * 16 + fr) * 32 + fk]);
        #pragma unroll
        for (int ni = 0; ni < 4; ++ni)
            bfr[ni] = *reinterpret_cast<const s16x8*>(&Bs[(wc * 64 + ni * 16 + fr) * 32 + fk]);
        #pragma unroll
        for (int mi = 0; mi < 4; ++mi)
            #pragma unroll
            for (int ni = 0; ni < 4; ++ni)
                acc[mi][ni] = __builtin_amdgcn_mfma_f32_16x16x32_bf16(
                    af[mi], bfr[ni], acc[mi][ni], 0, 0, 0);
        __syncthreads();
    }

    const int orow = (l >> 4) * 4;
    const int ocol = l & 15;
    #pragma unroll
    for (int mi = 0; mi < 4; ++mi) {
        #pragma unroll
        for (int ni = 0; ni < 4; ++ni) {
            int ib = i0 + wr * 64 + mi * 16 + orow;
            int jb = j0 + wc * 64 + ni * 16 + ocol;
            if constexpr (EPI == 0 || EPI == 1 || EPI == 4) {
                u16* D = (u16*)Dp;
                float bj = 0.f;
                if constexpr (EPI == 0) bj = bias[jb];
                #pragma unroll
                for (int e = 0; e < 4; ++e) {
                    float vv = acc[mi][ni][e];
                    if constexpr (EPI == 0) vv += bj;
                    if constexpr (EPI == 1) vv += bias[ib + e];
                    D[(size_t)(ib + e) * Nn + jb] = f2bf(vv);
                }
            } else if constexpr (EPI == 2) {
                float* D = (float*)Dp;
                #pragma unroll
                for (int e = 0; e < 4; ++e)
                    D[(size_t)(ib + e) * Nn + jb] = acc[mi][ni][e] * scl;
            } else {   // EPI == 3
                float* D = (float*)Dp;
                #pragma unroll
                for (int e = 0; e < 4; ++e)
                    D[(size_t)(ib + e) * Nn + jb] =
                        acc[mi][ni][e] + bias[ib + e] + resid[(size_t)(ib + e) * Nn + jb];
            }
        }
    }
}

// q_t/k_t: D[n][co] = sum_ci nx_t[n][ci] * W[co][ci] + b[co].  grid (4,32,8)
__global__ __launch_bounds__(256)
void qk_gemm(const u16* __restrict__ nx_t, const u16* __restrict__ wqb,
             const u16* __restrict__ wkb, const float* __restrict__ bq,
             const float* __restrict__ bk, u16* __restrict__ q_t,
             u16* __restrict__ k_t)
{
    int z = blockIdx.z, b = z & 3, isk = z >> 2;
    gemm_dev<0>(nx_t + (size_t)b * N_ * C_, isk ? wkb : wqb,
                (isk ? k_t : q_t) + (size_t)b * N_ * C_,
                isk ? bk : bq, nullptr, N_, C_, C_, C_, C_, 1.f);
}

// v: D[co][n] = sum_ci Wv[co][ci] * nx_t[n][ci] + bv[co].  grid (32,4,4)
__global__ __launch_bounds__(256)
void v_gemm(const u16* __restrict__ wvb, const u16* __restrict__ nx_t,
            const float* __restrict__ bv, u16* __restrict__ vbuf)
{
    int b = blockIdx.z;
    gemm_dev<1>(wvb, nx_t + (size_t)b * N_ * C_, vbuf + (size_t)b * C_ * N_,
                bv, nullptr, C_, N_, C_, C_, C_, 1.f);
}

// scores: S[i][j] = (sum_c q_t[i][c]*k_t[j][c]) / sqrt(C).  grid (32,32,2)
__global__ __launch_bounds__(256)
void scores_gemm(const u16* __restrict__ q_t, const u16* __restrict__ k_t,
                 float* __restrict__ S0, float* __restrict__ S1, int pair)
{
    int z = blockIdx.z, b = pair * 2 + z;
    gemm_dev<2>(q_t + (size_t)b * N_ * C_, k_t + (size_t)b * N_ * C_,
                z ? S1 : S0, nullptr, nullptr, N_, N_, C_, C_, C_,
                0.044194173824159216f);
}

// Row softmax over j; writes P bf16 into the FIRST HALF of each fp32 S row
// (same block that read the row -> no cross-block aliasing). grid (4096, 2)
__global__ __launch_bounds__(256)
void softmax_kernel(float* __restrict__ S0, float* __restrict__ S1)
{
    float* row = (blockIdx.y ? S1 : S0) + (size_t)blockIdx.x * N_;
    int t = threadIdx.x;
    __shared__ float red[256];

    float4 v[4];
    float mx = -1e30f;
    #pragma unroll
    for (int e = 0; e < 4; ++e) {
        v[e] = *reinterpret_cast<const float4*>(row + e * 1024 + t * 4);
        mx = fmaxf(mx, fmaxf(fmaxf(v[e].x, v[e].y), fmaxf(v[e].z, v[e].w)));
    }
    red[t] = mx; __syncthreads();
    for (int off = 128; off > 0; off >>= 1) {
        if (t < off) red[t] = fmaxf(red[t], red[t + off]);
        __syncthreads();
    }
    mx = red[0];
    __syncthreads();

    float sum = 0.f;
    #pragma unroll
    for (int e = 0; e < 4; ++e) {
        v[e].x = __expf(v[e].x - mx); v[e].y = __expf(v[e].y - mx);
        v[e].z = __expf(v[e].z - mx); v[e].w = __expf(v[e].w - mx);
        sum += v[e].x + v[e].y + v[e].z + v[e].w;
    }
    red[t] = sum; __syncthreads();
    for (int off = 128; off > 0; off >>= 1) {
        if (t < off) red[t] += red[t + off];
        __syncthreads();
    }
    float inv = 1.f / red[0];

    u16* P = (u16*)row;     // bf16 row, stride 2*N_ u16 across rows
    #pragma unroll
    for (int e = 0; e < 4; ++e) {
        int j = e * 1024 + t * 4;
        u16x4 o = { f2bf(v[e].x * inv), f2bf(v[e].y * inv),
                    f2bf(v[e].z * inv), f2bf(v[e].w * inv) };
        *reinterpret_cast<u16x4*>(P + j) = o;
    }
}

// PV: attn_t[i][c] = sum_j P[i][j] * v[c][j].  P lda = 2*N_ (in-place rows).
// grid (4, 32, 2)
__global__ __launch_bounds__(256)
void pv_gemm(const float* __restrict__ S0, const float* __restrict__ S1,
             const u16* __restrict__ vbuf, u16* __restrict__ attn_t, int pair)
{
    int z = blockIdx.z, b = pair * 2 + z;
    const u16* P = (const u16*)(z ? S1 : S0);
    gemm_dev<4>(P, vbuf + (size_t)b * C_ * N_, attn_t + (size_t)b * N_ * C_,
                nullptr, nullptr, N_, C_, N_, 2 * N_, N_, 1.f);
}

// final: out[co][n] = x + bo[co] + sum_ci wo[co][ci]*attn_t[n][ci]. grid (32,4,4)
__global__ __launch_bounds__(256)
void final_gemm(const u16* __restrict__ wob, const u16* __restrict__ attn_t,
                const float* __restrict__ bo, const float* __restrict__ x,
                float* __restrict__ outp)
{
    int b = blockIdx.z;
    gemm_dev<3>(wob, attn_t + (size_t)b * N_ * C_, outp + (size_t)b * C_ * N_,
                bo, x + (size_t)b * C_ * N_, C_, N_, C_, C_, C_, 1.f);
}

// ---------------------------------------------------------------------------
extern "C" void kernel_launch(void* const* d_in, const int* in_sizes, int n_in,
                              void* d_out, int out_size, void* d_ws, size_t ws_size,
                              hipStream_t stream)
{
    const float* x     = (const float*)d_in[0];
    const float* gamma = (const float*)d_in[1];
    const float* beta  = (const float*)d_in[2];
    const float* wq    = (const float*)d_in[3];
    const float* bq    = (const float*)d_in[4];
    const float* wk    = (const float*)d_in[5];
    const float* bk    = (const float*)d_in[6];
    const float* wv    = (const float*)d_in[7];
    const float* bv    = (const float*)d_in[8];
    const float* wo    = (const float*)d_in[9];
    const float* bo    = (const float*)d_in[10];
    float* out = (float*)d_out;

    // Workspace carve (total ~194 MB):
    char* p = (char*)d_ws;
    auto take = [&](size_t bytes) { char* r = p; p += (bytes + 255) & ~(size_t)255; return r; };
    float* scale = (float*)take(B_ * C_ * 4);
    float* shift = (float*)take(B_ * C_ * 4);
    u16* wqb = (u16*)take((size_t)C_ * C_ * 2);
    u16* wkb = (u16*)take((size_t)C_ * C_ * 2);
    u16* wvb = (u16*)take((size_t)C_ * C_ * 2);
    u16* wob = (u16*)take((size_t)C_ * C_ * 2);
    u16* nx_t  = (u16*)take((size_t)B_ * N_ * C_ * 2);   // also reused as attn_t
    u16* q_t   = (u16*)take((size_t)B_ * N_ * C_ * 2);
    u16* k_t   = (u16*)take((size_t)B_ * N_ * C_ * 2);
    u16* vbuf  = (u16*)take((size_t)B_ * C_ * N_ * 2);
    float* S0  = (float*)take((size_t)N_ * N_ * 4);
    float* S1  = (float*)take((size_t)N_ * N_ * 4);
    u16* attn_t = nx_t;    // nx_t is dead after qkv projections

    gn_stats_kernel<<<128, 256, 0, stream>>>(x, gamma, beta, scale, shift);
    wcvt_kernel<<<256, 256, 0, stream>>>(wq, wk, wv, wo, wqb, wkb, wvb, wob);
    nxt_kernel<<<dim3(N_ / 64, C_ / 64, B_), 256, 0, stream>>>(x, scale, shift, nx_t);

    qk_gemm<<<dim3(C_ / 128, N_ / 128, 8), 256, 0, stream>>>(nx_t, wqb, wkb, bq, bk, q_t, k_t);
    v_gemm<<<dim3(N_ / 128, C_ / 128, B_), 256, 0, stream>>>(wvb, nx_t, bv, vbuf);

    for (int pair = 0; pair < 2; ++pair) {
        scores_gemm<<<dim3(N_ / 128, N_ / 128, 2), 256, 0, stream>>>(q_t, k_t, S0, S1, pair);
        softmax_kernel<<<dim3(N_, 2), 256, 0, stream>>>(S0, S1);
        pv_gemm<<<dim3(C_ / 128, N_ / 128, 2), 256, 0, stream>>>(S0, S1, vbuf, attn_t, pair);
    }

    final_gemm<<<dim3(N_ / 128, C_ / 128, B_), 256, 0, stream>>>(wob, attn_t, bo, x, out);
}